// Round 1
// baseline (628.672 us; speedup 1.0000x reference)
//
#include <hip/hip_runtime.h>
#include <hip/hip_bf16.h>

// Problem constants (from reference): D=64 (== wave width), segment_ids sorted.
#define D 64

// Kernel 1: compute segment start offsets from sorted segment_ids.
// starts[s] = first edge index e with segment_ids[e] >= s, for s in [0, nseg].
// Handles empty segments: thread e fills all s in (sids[e-1], sids[e]].
__global__ __launch_bounds__(256) void seg_starts_kernel(
    const int* __restrict__ sids, int E, int nseg, int* __restrict__ starts) {
    int e = blockIdx.x * blockDim.x + threadIdx.x;
    if (e >= E) return;
    int cur = sids[e];
    int prev = (e == 0) ? -1 : sids[e - 1];
    for (int s = prev + 1; s <= cur; ++s) starts[s] = e;
    if (e == E - 1) {
        for (int s = cur + 1; s <= nseg; ++s) starts[s] = E;
    }
}

// Kernel 2: one wave (64 lanes) per segment; lane i owns feature dim i.
// Each edge is one coalesced 256B row read. Indices batch-loaded 64 at a
// time per wave and broadcast via shfl.
__global__ __launch_bounds__(256) void seg_mean_kernel(
    const float* __restrict__ vals, const int* __restrict__ gidx,
    const int* __restrict__ sids, const int* __restrict__ starts,
    float* __restrict__ out, int E, int nseg) {
    int lane = threadIdx.x & 63;
    int seg = blockIdx.x * (blockDim.x >> 6) + (threadIdx.x >> 6);
    if (seg >= nseg) return;

    int start, end;
    if (starts) {
        start = starts[seg];
        end = starts[seg + 1];
    } else {
        // Fallback: binary search lower_bound(seg) and lower_bound(seg+1).
        int lo = 0, hi = E;
        while (lo < hi) { int mid = (lo + hi) >> 1; if (sids[mid] < seg) lo = mid + 1; else hi = mid; }
        start = lo;
        int lo2 = start, hi2 = E;
        while (lo2 < hi2) { int mid = (lo2 + hi2) >> 1; if (sids[mid] < seg + 1) lo2 = mid + 1; else hi2 = mid; }
        end = lo2;
    }

    float acc = 0.0f;
    for (int base = start; base < end; base += 64) {
        int n = end - base;
        if (n > 64) n = 64;
        int my = 0;
        if (lane < n) my = gidx[base + lane];   // one coalesced 256B idx load / 64 edges
        for (int j = 0; j < n; ++j) {
            int idx = __shfl(my, j, 64);
            acc += vals[(size_t)idx * D + lane]; // coalesced 256B row read per edge
        }
    }
    int cnt = end - start;
    float denom = (cnt > 0) ? (float)cnt : 1.0f;
    out[(size_t)seg * D + lane] = acc / denom;
}

extern "C" void kernel_launch(void* const* d_in, const int* in_sizes, int n_in,
                              void* d_out, int out_size, void* d_ws, size_t ws_size,
                              hipStream_t stream) {
    const float* vals = (const float*)d_in[0];   // [N_SRC, 64] fp32
    const int*   gidx = (const int*)d_in[1];     // [E] int32
    const int*   sids = (const int*)d_in[2];     // [E] int32, sorted
    float*       out  = (float*)d_out;           // [nseg, 64] fp32

    int E = in_sizes[1];
    int nseg = out_size / D;

    int* starts = nullptr;
    size_t need = (size_t)(nseg + 1) * sizeof(int);
    if (ws_size >= need) {
        starts = (int*)d_ws;
        int blocks = (E + 255) / 256;
        seg_starts_kernel<<<blocks, 256, 0, stream>>>(sids, E, nseg, starts);
    }

    const int waves_per_block = 4;
    int blocks2 = (nseg + waves_per_block - 1) / waves_per_block;
    seg_mean_kernel<<<blocks2, waves_per_block * 64, 0, stream>>>(
        vals, gidx, sids, starts, out, E, nseg);
}

// Round 2
// 468.747 us; speedup vs baseline: 1.3412x; 1.3412x over previous
//
#include <hip/hip_runtime.h>

// Problem: out[s,:] = mean_{e: sid[e]==s} vals[gidx[e],:], D=64, sids sorted.
// D == 64 floats == 16 float4. Wave layout: lane = (sub, c), sub=lane>>4 picks
// one of 4 edges processed concurrently, c=lane&15 picks the float4 column.
// One load instruction = 64 lanes x 16B = 4 full rows = 4 edges.
#define D 64

// starts[s] = first edge index with sids[e] >= s, s in [0, nseg].
__global__ __launch_bounds__(256) void seg_starts_kernel(
    const int* __restrict__ sids, int E, int nseg, int* __restrict__ starts) {
    int e = blockIdx.x * blockDim.x + threadIdx.x;
    if (e >= E) return;
    int cur = sids[e];
    int prev = (e == 0) ? -1 : sids[e - 1];
    for (int s = prev + 1; s <= cur; ++s) starts[s] = e;
    if (e == E - 1) {
        for (int s = cur + 1; s <= nseg; ++s) starts[s] = E;
    }
}

__device__ __forceinline__ void acc4(float4& a, const float4& v) {
    a.x += v.x; a.y += v.y; a.z += v.z; a.w += v.w;
}

// One wave per segment. 4 edges per load instruction, up to 16 edges in
// flight (4 independent float4 loads) before the accumulate waitcnt.
__global__ __launch_bounds__(256) void seg_mean_kernel(
    const float4* __restrict__ vals4, const int* __restrict__ gidx,
    const int* __restrict__ sids, const int* __restrict__ starts,
    float4* __restrict__ out4, int E, int nseg) {
    int lane = threadIdx.x & 63;
    int seg = blockIdx.x * (blockDim.x >> 6) + (threadIdx.x >> 6);
    if (seg >= nseg) return;
    int sub = lane >> 4;   // edge subgroup 0..3
    int c   = lane & 15;   // float4 column 0..15

    int start, end;
    if (starts) {
        start = starts[seg];
        end   = starts[seg + 1];
    } else {
        int lo = 0, hi = E;
        while (lo < hi) { int m = (lo + hi) >> 1; if (sids[m] < seg) lo = m + 1; else hi = m; }
        start = lo;
        int lo2 = start, hi2 = E;
        while (lo2 < hi2) { int m = (lo2 + hi2) >> 1; if (sids[m] < seg + 1) lo2 = m + 1; else hi2 = m; }
        end = lo2;
    }
    int cnt = end - start;

    float4 a0 = {0,0,0,0}, a1 = {0,0,0,0}, a2 = {0,0,0,0}, a3 = {0,0,0,0};

    for (int base = start; base < end; base += 64) {
        int n = end - base;
        if (n > 64) n = 64;
        int my = 0;
        if (lane < n) my = gidx[base + lane];  // one coalesced idx load / 64 edges

        int j = 0;
        // Main: 16 edges per iteration, 4 independent 1KB loads in flight.
        for (; j + 16 <= n; j += 16) {
            int i0 = __shfl(my, j +  0 + sub, 64);
            int i1 = __shfl(my, j +  4 + sub, 64);
            int i2 = __shfl(my, j +  8 + sub, 64);
            int i3 = __shfl(my, j + 12 + sub, 64);
            float4 v0 = vals4[(size_t)i0 * 16 + c];
            float4 v1 = vals4[(size_t)i1 * 16 + c];
            float4 v2 = vals4[(size_t)i2 * 16 + c];
            float4 v3 = vals4[(size_t)i3 * 16 + c];
            acc4(a0, v0); acc4(a1, v1); acc4(a2, v2); acc4(a3, v3);
        }
        // 8-edge step: 2 independent loads.
        if (j + 8 <= n) {
            int i0 = __shfl(my, j + 0 + sub, 64);
            int i1 = __shfl(my, j + 4 + sub, 64);
            float4 v0 = vals4[(size_t)i0 * 16 + c];
            float4 v1 = vals4[(size_t)i1 * 16 + c];
            acc4(a0, v0); acc4(a1, v1);
            j += 8;
        }
        // Tail: up to 4 edges, predicated per-subgroup.
        for (; j < n; j += 4) {
            int jj = j + sub;
            int src = (jj < n) ? jj : (n - 1);
            int idx = __shfl(my, src, 64);  // all lanes active for shfl
            if (jj < n) {
                float4 v = vals4[(size_t)idx * 16 + c];
                acc4(a0, v);
            }
        }
    }

    acc4(a0, a1); acc4(a2, a3); acc4(a0, a2);
    // Reduce across the 4 edge subgroups (lanes differing in bits 4,5).
    a0.x += __shfl_xor(a0.x, 16, 64); a0.y += __shfl_xor(a0.y, 16, 64);
    a0.z += __shfl_xor(a0.z, 16, 64); a0.w += __shfl_xor(a0.w, 16, 64);
    a0.x += __shfl_xor(a0.x, 32, 64); a0.y += __shfl_xor(a0.y, 32, 64);
    a0.z += __shfl_xor(a0.z, 32, 64); a0.w += __shfl_xor(a0.w, 32, 64);

    float inv = 1.0f / (float)((cnt > 0) ? cnt : 1);
    if (sub == 0) {
        float4 r;
        r.x = a0.x * inv; r.y = a0.y * inv; r.z = a0.z * inv; r.w = a0.w * inv;
        out4[(size_t)seg * 16 + c] = r;  // 16 lanes x 16B = one 256B row
    }
}

extern "C" void kernel_launch(void* const* d_in, const int* in_sizes, int n_in,
                              void* d_out, int out_size, void* d_ws, size_t ws_size,
                              hipStream_t stream) {
    const float* vals = (const float*)d_in[0];   // [N_SRC, 64] fp32
    const int*   gidx = (const int*)d_in[1];     // [E] int32
    const int*   sids = (const int*)d_in[2];     // [E] int32, sorted
    float*       out  = (float*)d_out;           // [nseg, 64] fp32

    int E = in_sizes[1];
    int nseg = out_size / D;

    int* starts = nullptr;
    size_t need = (size_t)(nseg + 1) * sizeof(int);
    if (ws_size >= need) {
        starts = (int*)d_ws;
        int blocks = (E + 255) / 256;
        seg_starts_kernel<<<blocks, 256, 0, stream>>>(sids, E, nseg, starts);
    }

    const int waves_per_block = 4;
    int blocks2 = (nseg + waves_per_block - 1) / waves_per_block;
    seg_mean_kernel<<<blocks2, waves_per_block * 64, 0, stream>>>(
        (const float4*)vals, gidx, sids, starts, (float4*)out, E, nseg);
}

// Round 6
// 463.171 us; speedup vs baseline: 1.3573x; 1.0120x over previous
//
#include <hip/hip_runtime.h>

// out[s,:] = mean_{e: sid[e]==s} vals[gidx[e],:], D=64 fp32, sids sorted.
// Wave layout: lane = (sub, c): sub=lane>>4 -> one of 4 edges per load inst,
// c=lane&15 -> float4 column. One dwordx4 load = 4 full 256B rows = 4 edges.
// ROW STRIDE = 64 floats * 4B = 256B -> byte offset is idx<<8 (NOT <<10 —
// that 4x-OOB slip was the R4/R5 abort).
// Streaming data (gidx, out) uses non-temporal hints so the 256MB table keeps
// the 256MB L3; table loads stay cached (4x average reuse).
#define D 64

// Native vector type: __builtin_nontemporal_* requires scalar/native-vector,
// not HIP's struct-based float4.
typedef float vfloat4 __attribute__((ext_vector_type(4)));

// starts[s] = first edge index with sids[e] >= s, s in [0, nseg].
__global__ __launch_bounds__(256) void seg_starts_kernel(
    const int* __restrict__ sids, int E, int nseg, int* __restrict__ starts) {
    int e = blockIdx.x * blockDim.x + threadIdx.x;
    if (e >= E) return;
    int cur = __builtin_nontemporal_load(&sids[e]);
    int prev = (e == 0) ? -1 : __builtin_nontemporal_load(&sids[e - 1]);
    for (int s = prev + 1; s <= cur; ++s) starts[s] = e;
    if (e == E - 1) {
        for (int s = cur + 1; s <= nseg; ++s) starts[s] = E;
    }
}

// One wave per segment. starts==nullptr -> in-kernel binary search fallback
// (only when ws_size can't hold the starts array).
__global__ __launch_bounds__(256) void seg_mean_kernel(
    const float* __restrict__ vals, const int* __restrict__ gidx,
    const int* __restrict__ sids, const int* __restrict__ starts,
    float* __restrict__ out, int E, int nseg) {
    int lane = threadIdx.x & 63;
    int seg = blockIdx.x * (blockDim.x >> 6) + (threadIdx.x >> 6);
    if (seg >= nseg) return;
    int sub = lane >> 4;          // edge subgroup 0..3
    int c16 = (lane & 15) << 4;   // float4 column byte offset 0..240

    int start, end;
    if (starts) {
        start = starts[seg];
        end   = starts[seg + 1];
    } else {
        int lo = 0, hi = E;
        while (lo < hi) { int m = (lo + hi) >> 1; if (sids[m] < seg) lo = m + 1; else hi = m; }
        start = lo;
        int lo2 = start, hi2 = E;
        while (lo2 < hi2) { int m = (lo2 + hi2) >> 1; if (sids[m] < seg + 1) lo2 = m + 1; else hi2 = m; }
        end = lo2;
    }
    int cnt = end - start;

    const char* vbase = (const char*)vals;  // 256MB table: 32-bit byte offsets fit
    vfloat4 a0 = {0,0,0,0}, a1 = {0,0,0,0}, a2 = {0,0,0,0}, a3 = {0,0,0,0};

    for (int base = start; base < end; base += 64) {
        int n = end - base;
        if (n > 64) n = 64;
        // Coalesced idx load, clamped (branchless).
        int l = (lane < n) ? lane : (n - 1);
        int my = __builtin_nontemporal_load(&gidx[base + l]);

        int j = 0;
        // Main: 16 edges per pass, 4 independent 1KB loads in flight.
        for (; j + 16 <= n; j += 16) {
            int i0 = __shfl(my, j +  0 + sub, 64);
            int i1 = __shfl(my, j +  4 + sub, 64);
            int i2 = __shfl(my, j +  8 + sub, 64);
            int i3 = __shfl(my, j + 12 + sub, 64);
            vfloat4 v0 = *(const vfloat4*)(vbase + (((unsigned)i0 << 8) | c16));
            vfloat4 v1 = *(const vfloat4*)(vbase + (((unsigned)i1 << 8) | c16));
            vfloat4 v2 = *(const vfloat4*)(vbase + (((unsigned)i2 << 8) | c16));
            vfloat4 v3 = *(const vfloat4*)(vbase + (((unsigned)i3 << 8) | c16));
            a0 += v0; a1 += v1; a2 += v2; a3 += v3;
        }
        // Remainder (<16 edges): one branchless predicated pass, 4 loads in
        // flight, clamped shfl lane + mask-mul (invalid edges contribute 0).
        if (j < n) {
            int e0 = j + sub, e1 = j + 4 + sub, e2 = j + 8 + sub, e3 = j + 12 + sub;
            int s0 = (e0 < n) ? e0 : (n - 1);
            int s1 = (e1 < n) ? e1 : (n - 1);
            int s2 = (e2 < n) ? e2 : (n - 1);
            int s3 = (e3 < n) ? e3 : (n - 1);
            int i0 = __shfl(my, s0, 64);
            int i1 = __shfl(my, s1, 64);
            int i2 = __shfl(my, s2, 64);
            int i3 = __shfl(my, s3, 64);
            vfloat4 v0 = *(const vfloat4*)(vbase + (((unsigned)i0 << 8) | c16));
            vfloat4 v1 = *(const vfloat4*)(vbase + (((unsigned)i1 << 8) | c16));
            vfloat4 v2 = *(const vfloat4*)(vbase + (((unsigned)i2 << 8) | c16));
            vfloat4 v3 = *(const vfloat4*)(vbase + (((unsigned)i3 << 8) | c16));
            a0 += v0 * ((e0 < n) ? 1.0f : 0.0f);
            a1 += v1 * ((e1 < n) ? 1.0f : 0.0f);
            a2 += v2 * ((e2 < n) ? 1.0f : 0.0f);
            a3 += v3 * ((e3 < n) ? 1.0f : 0.0f);
        }
    }

    a0 += a1; a2 += a3; a0 += a2;
    // Reduce across the 4 edge subgroups (lane bits 4,5).
    a0.x += __shfl_xor(a0.x, 16, 64); a0.y += __shfl_xor(a0.y, 16, 64);
    a0.z += __shfl_xor(a0.z, 16, 64); a0.w += __shfl_xor(a0.w, 16, 64);
    a0.x += __shfl_xor(a0.x, 32, 64); a0.y += __shfl_xor(a0.y, 32, 64);
    a0.z += __shfl_xor(a0.z, 32, 64); a0.w += __shfl_xor(a0.w, 32, 64);

    float inv = 1.0f / (float)((cnt > 0) ? cnt : 1);
    if (sub == 0) {
        vfloat4 r = a0 * inv;
        // 16 lanes x 16B = one 256B out row; NT store: written once, never read.
        __builtin_nontemporal_store(r, (vfloat4*)((char*)out + (((unsigned)seg << 8) | c16)));
    }
}

extern "C" void kernel_launch(void* const* d_in, const int* in_sizes, int n_in,
                              void* d_out, int out_size, void* d_ws, size_t ws_size,
                              hipStream_t stream) {
    const float* vals = (const float*)d_in[0];   // [N_SRC, 64] fp32
    const int*   gidx = (const int*)d_in[1];     // [E] int32
    const int*   sids = (const int*)d_in[2];     // [E] int32, sorted
    float*       out  = (float*)d_out;           // [nseg, 64] fp32

    int E = in_sizes[1];
    int nseg = out_size / D;

    int* starts = nullptr;
    size_t need = (size_t)(nseg + 1) * sizeof(int);
    if (ws_size >= need) {
        starts = (int*)d_ws;
        int blocks = (E + 255) / 256;
        seg_starts_kernel<<<blocks, 256, 0, stream>>>(sids, E, nseg, starts);
    }

    const int waves_per_block = 4;
    int blocks2 = (nseg + waves_per_block - 1) / waves_per_block;
    seg_mean_kernel<<<blocks2, waves_per_block * 64, 0, stream>>>(
        vals, gidx, sids, starts, out, E, nseg);
}